// Round 2
// baseline (229.601 us; speedup 1.0000x reference)
//
#include <hip/hip_runtime.h>

// Problem constants (N=32, T=1024 -> NTOK tokens). All I/O is FP32 per the
// reference; MFMA compute path converts to bf16 (RNE) with fp32 accumulation.
#define NTOK  32768
#define CIN   64
#define HDIM  128
#define O_CH  16
#define F2    16
#define TB    64          // tokens per block
#define SLOPE 0.01f
#define EPS   1e-5f

// LDS layout (in bf16/short elements). Row strides padded so every row start
// is 16B-aligned (stride % 8 == 0) and rotates 4 banks/row -> ds_read_b128
// friendly. SW0 region is DEAD after layer 0 and is reused as the h-buffer
// (guarded by a __syncthreads). Total = 28800 shorts = 57600 B (<64KB/WG,
// 2 blocks/CU at 160KB LDS).
#define SW0_STRIDE 72     // 64 + 8
#define SW1_STRIDE 136    // 128 + 8
#define SW2_STRIDE 136
#define SH_STRIDE  136

#define SW0_OFF 0                       // 128 x 72  = 9216 shorts
#define SH_OFF  0                       // 64 x 136 = 8704 shorts (reuses SW0)
#define SW1_OFF 9216                    // 128 x 136 = 17408 shorts
#define SW2_OFF (9216 + 17408)          // 16  x 136 = 2176 shorts
#define SMEM_TOT (9216 + 17408 + 2176)  // 28800 shorts = 57600 B

typedef __attribute__((ext_vector_type(8))) short bf16x8;   // 8 bf16 = 4 VGPRs
typedef __attribute__((ext_vector_type(4))) float f32x4;    // MFMA C/D frag

__device__ __forceinline__ float b2f(unsigned short u) {
  union { unsigned int i; float f; } v;
  v.i = ((unsigned int)u) << 16;
  return v.f;
}
__device__ __forceinline__ unsigned short f2b(float f) {
  union { float f; unsigned int i; } v;
  v.f = f;
  unsigned int i = v.i;
  // round-to-nearest-even bf16
  unsigned int r = (i + 0x7fffu + ((i >> 16) & 1u)) >> 16;
  return (unsigned short)r;
}
__device__ __forceinline__ float leaky(float t) {
  return (t >= 0.f) ? t : SLOPE * t;
}
// convert 8 contiguous fp32 -> one bf16x8 (RNE)
__device__ __forceinline__ bf16x8 cvt8(const float* __restrict__ p) {
  float4 a = *(const float4*)p;
  float4 b = *(const float4*)(p + 4);
  bf16x8 r;
  r[0] = (short)f2b(a.x); r[1] = (short)f2b(a.y);
  r[2] = (short)f2b(a.z); r[3] = (short)f2b(a.w);
  r[4] = (short)f2b(b.x); r[5] = (short)f2b(b.y);
  r[6] = (short)f2b(b.z); r[7] = (short)f2b(b.w);
  return r;
}

// bias + LeakyReLU + LayerNorm over H (=128, spread across 8 n-tiles), then
// store bf16 result to the LDS h-buffer in [token][h] layout.
// C/D layout of mfma_f32_16x16x32: col = lane&15, row = (lane>>4)*4 + reg.
// For a fixed token row, all 128 cols live in the 16 lanes of one quad-group
// -> 16-lane butterfly reduction via __shfl_xor (masks 1,2,4,8 stay in-group).
__device__ __forceinline__ void bias_leaky_ln_store(
    const f32x4* acc,
    const float* __restrict__ bias_g,
    const float* __restrict__ gamma_g,
    const float* __restrict__ beta_g,
    unsigned short* __restrict__ sh,
    int row0, int lo16, int quad) {
  float v[8][4];
  float s1[4] = {0.f, 0.f, 0.f, 0.f};
  float s2[4] = {0.f, 0.f, 0.f, 0.f};
#pragma unroll
  for (int nt = 0; nt < 8; ++nt) {
    float b = bias_g[nt * 16 + lo16];
#pragma unroll
    for (int r = 0; r < 4; ++r) {
      float t = leaky(acc[nt][r] + b);
      v[nt][r] = t;
      s1[r] += t;
      s2[r] += t * t;
    }
  }
#pragma unroll
  for (int r = 0; r < 4; ++r) {
#pragma unroll
    for (int m = 1; m < 16; m <<= 1) {
      s1[r] += __shfl_xor(s1[r], m);
      s2[r] += __shfl_xor(s2[r], m);
    }
  }
  float mu[4], rs[4];
#pragma unroll
  for (int r = 0; r < 4; ++r) {
    mu[r] = s1[r] * (1.0f / 128.0f);
    float var = s2[r] * (1.0f / 128.0f) - mu[r] * mu[r];
    rs[r] = rsqrtf(var + EPS);
  }
#pragma unroll
  for (int nt = 0; nt < 8; ++nt) {
    float g  = gamma_g[nt * 16 + lo16];
    float be = beta_g[nt * 16 + lo16];
#pragma unroll
    for (int r = 0; r < 4; ++r) {
      float y = (v[nt][r] - mu[r]) * rs[r] * g + be;
      sh[(row0 + quad * 4 + r) * SH_STRIDE + nt * 16 + lo16] = f2b(y);
    }
  }
}

__global__ __launch_bounds__(256, 2) void film_main(
    const float* __restrict__ x,
    const float* __restrict__ W0, const float* __restrict__ b0,
    const float* __restrict__ g0, const float* __restrict__ be0,
    const float* __restrict__ W1, const float* __restrict__ b1,
    const float* __restrict__ g1, const float* __restrict__ be1,
    const float* __restrict__ W2, const float* __restrict__ b2,
    float* __restrict__ outp, int staged) {
  __shared__ unsigned short smem[SMEM_TOT];
  const int tid  = threadIdx.x;
  const int o    = blockIdx.x & 15;
  const int tile = blockIdx.x >> 4;
  const int tok0 = tile * TB;

  // ---- Phase A: stage this o-channel's weights into LDS, fp32 -> bf16.
  // Native [n][k] layout == MFMA B-fragment layout; rows padded.
  {
    const float* s0 = W0 + (size_t)o * HDIM * CIN;
    for (int c = tid; c < (HDIM * CIN) / 8; c += 256) {       // 1024 chunks
      int n = c >> 3, k8 = c & 7;
      *(bf16x8*)&smem[SW0_OFF + n * SW0_STRIDE + k8 * 8] = cvt8(s0 + c * 8);
    }
    const float* s1p = W1 + (size_t)o * HDIM * HDIM;
    for (int c = tid; c < (HDIM * HDIM) / 8; c += 256) {      // 2048 chunks
      int n = c >> 4, k8 = c & 15;
      *(bf16x8*)&smem[SW1_OFF + n * SW1_STRIDE + k8 * 8] = cvt8(s1p + c * 8);
    }
    const float* s2p = W2 + (size_t)o * F2 * HDIM;
    for (int c = tid; c < (F2 * HDIM) / 8; c += 256) {        // 256 chunks
      int n = c >> 4, k8 = c & 15;
      *(bf16x8*)&smem[SW2_OFF + n * SW2_STRIDE + k8 * 8] = cvt8(s2p + c * 8);
    }
  }
  __syncthreads();

  const int lane = tid & 63;
  const int wave = tid >> 6;
  const int lo16 = lane & 15;
  const int quad = lane >> 4;
  const int row0 = wave * 16;   // this wave's 16-token M-tile within the block

  // ---- Layer 0: [64 tok x 64] @ W0^T -> [64 tok x 128]
  // A-frag: A[m=lane&15][k=quad*8+j] read from global x (fp32 -> bf16).
  f32x4 acc[8];
#pragma unroll
  for (int nt = 0; nt < 8; ++nt) acc[nt] = (f32x4){0.f, 0.f, 0.f, 0.f};
  {
    const float* xrow = x + (size_t)(tok0 + row0 + lo16) * CIN + quad * 8;
#pragma unroll
    for (int ks = 0; ks < 2; ++ks) {
      bf16x8 a = cvt8(xrow + ks * 32);
#pragma unroll
      for (int nt = 0; nt < 8; ++nt) {
        bf16x8 b = *(const bf16x8*)
            &smem[SW0_OFF + (nt * 16 + lo16) * SW0_STRIDE + ks * 32 + quad * 8];
        acc[nt] = __builtin_amdgcn_mfma_f32_16x16x32_bf16(a, b, acc[nt], 0, 0, 0);
      }
    }
  }
  // SW0 region is reused as the h-buffer: ALL waves must finish their layer-0
  // B-fragment reads before ANY wave writes h.
  __syncthreads();
  bias_leaky_ln_store(acc, b0 + o * HDIM, g0 + o * HDIM, be0 + o * HDIM,
                      smem + SH_OFF, row0, lo16, quad);

  // ---- Layer 1: [64 tok x 128] @ W1^T -> [64 tok x 128]
  // h rows are wave-local (rows row0..row0+15 written and read by this wave
  // only; DS ops are in-order within a wave) -> no barrier needed.
#pragma unroll
  for (int nt = 0; nt < 8; ++nt) acc[nt] = (f32x4){0.f, 0.f, 0.f, 0.f};
#pragma unroll
  for (int ks = 0; ks < 4; ++ks) {
    bf16x8 a = *(const bf16x8*)
        &smem[SH_OFF + (row0 + lo16) * SH_STRIDE + ks * 32 + quad * 8];
#pragma unroll
    for (int nt = 0; nt < 8; ++nt) {
      bf16x8 b = *(const bf16x8*)
          &smem[SW1_OFF + (nt * 16 + lo16) * SW1_STRIDE + ks * 32 + quad * 8];
      acc[nt] = __builtin_amdgcn_mfma_f32_16x16x32_bf16(a, b, acc[nt], 0, 0, 0);
    }
  }
  bias_leaky_ln_store(acc, b1 + o * HDIM, g1 + o * HDIM, be1 + o * HDIM,
                      smem + SH_OFF, row0, lo16, quad);

  // ---- Layer 2: [64 tok x 128] @ W2^T -> [64 tok x 16]
  f32x4 acc2 = (f32x4){0.f, 0.f, 0.f, 0.f};
#pragma unroll
  for (int ks = 0; ks < 4; ++ks) {
    bf16x8 a = *(const bf16x8*)
        &smem[SH_OFF + (row0 + lo16) * SH_STRIDE + ks * 32 + quad * 8];
    bf16x8 b = *(const bf16x8*)
        &smem[SW2_OFF + lo16 * SW2_STRIDE + ks * 32 + quad * 8];
    acc2 = __builtin_amdgcn_mfma_f32_16x16x32_bf16(a, b, acc2, 0, 0, 0);
  }
  {
    float bb = b2[o * F2 + lo16];
#pragma unroll
    for (int r = 0; r < 4; ++r) {
      float y = leaky(acc2[r] + bb);
      int token = tok0 + row0 + quad * 4 + r;   // f = lo16
      if (staged) {
        // staging [o][token][f]: each 16-lane group writes 64B contiguous
        outp[(size_t)o * NTOK * F2 + (size_t)token * F2 + lo16] = y;
      } else {
        // direct (N,T,F2,O) scatter fallback (64B-stride, slow but correct)
        outp[(size_t)token * (F2 * O_CH) + lo16 * O_CH + o] = y;
      }
    }
  }
}

// stage [o][token][f] -> out [token][f][o], coalesced both ways via LDS tile.
__global__ __launch_bounds__(256) void transpose_out(
    const float* __restrict__ stg, float* __restrict__ out) {
  __shared__ float tilebuf[16 * 256];   // 16 KB
  const int tid = threadIdx.x;
  const int t0  = blockIdx.x * 16;
  const int o   = tid >> 4;
  const int f   = tid & 15;
#pragma unroll
  for (int i = 0; i < 16; ++i) {
    float v = stg[(size_t)o * NTOK * F2 + (size_t)(t0 + i) * F2 + f];
    tilebuf[i * 256 + f * O_CH + o] = v;
  }
  __syncthreads();
  const size_t base = (size_t)t0 * 256;
#pragma unroll
  for (int i = 0; i < 16; ++i) {
    out[base + i * 256 + tid] = tilebuf[i * 256 + tid];
  }
}

extern "C" void kernel_launch(void* const* d_in, const int* in_sizes, int n_in,
                              void* d_out, int out_size, void* d_ws, size_t ws_size,
                              hipStream_t stream) {
  (void)in_sizes; (void)n_in; (void)out_size;
  const float* x   = (const float*)d_in[0];
  const float* W0  = (const float*)d_in[1];
  const float* b0  = (const float*)d_in[2];
  const float* g0  = (const float*)d_in[3];
  const float* be0 = (const float*)d_in[4];
  const float* W1  = (const float*)d_in[5];
  const float* b1  = (const float*)d_in[6];
  const float* g1  = (const float*)d_in[7];
  const float* be1 = (const float*)d_in[8];
  const float* W2  = (const float*)d_in[9];
  const float* b2  = (const float*)d_in[10];

  const size_t stage_bytes = (size_t)O_CH * NTOK * F2 * sizeof(float);
  const int staged = (ws_size >= stage_bytes) ? 1 : 0;
  float* outp = staged ? (float*)d_ws : (float*)d_out;

  film_main<<<dim3(O_CH * (NTOK / TB)), dim3(256), 0, stream>>>(
      x, W0, b0, g0, be0, W1, b1, g1, be1, W2, b2, outp, staged);
  if (staged) {
    transpose_out<<<dim3(NTOK / 16), dim3(256), 0, stream>>>(
        (const float*)d_ws, (float*)d_out);
  }
}

// Round 3
// 198.871 us; speedup vs baseline: 1.1545x; 1.1545x over previous
//
#include <hip/hip_runtime.h>

// Problem constants (N=32, T=1024 -> NTOK tokens). I/O fp32; compute path is
// bf16 MFMA with fp32 accumulation. Verified-correct layouts from R2.
#define NTOK  32768
#define CIN   64
#define HDIM  128
#define O_CH  16
#define F2    16
#define SLOPE 0.01f
#define EPS   1e-5f

// LDS weight image (in shorts). Rows padded: 16B-aligned starts, 4-bank
// rotation per row (2-way conflict max on ds_read_b128 = free per m136).
// This exact image is PREBUILT in d_ws by the prep kernel, so film_main's
// staging is a straight contiguous 57.6 KB copy.
#define SW0_STRIDE 72     // 64 + 8
#define SW1_STRIDE 136    // 128 + 8
#define SW2_STRIDE 136
#define SH_STRIDE  136
#define SW0_OFF 0                       // 128 x 72  = 9216 shorts
#define SW1_OFF 9216                    // 128 x 136 = 17408 shorts
#define SW2_OFF (9216 + 17408)          // 16  x 136 = 2176 shorts -> 26624
#define WIMG_SHORTS 28800               // 57600 B per o-channel
#define SH_OFF  28800                   // h-buffer: 64 rows x 136
#define SMEM_TOT (28800 + 64 * SH_STRIDE)   // 37504 shorts = 75008 B -> 2 blk/CU

// d_ws layout (bytes). Proven ws >= 33.5 MB in R2; we need only 21.9 MB.
#define STG_OFF   0
#define STG_BYTES ((size_t)O_CH * NTOK * F2 * 2)            // 16777216
#define WIMG_OFF  STG_BYTES
#define WIMG_BYTES ((size_t)O_CH * WIMG_SHORTS * 2)         // 921600
#define XBF_OFF   (WIMG_OFF + WIMG_BYTES)
#define XBF_BYTES ((size_t)NTOK * CIN * 2)                  // 4194304

typedef __attribute__((ext_vector_type(8))) short bf16x8;   // 8 bf16 = 4 VGPRs
typedef __attribute__((ext_vector_type(4))) float f32x4;    // MFMA C/D frag

__device__ __forceinline__ float b2f(unsigned short u) {
  union { unsigned int i; float f; } v;
  v.i = ((unsigned int)u) << 16;
  return v.f;
}
__device__ __forceinline__ unsigned short f2b(float f) {
  union { float f; unsigned int i; } v;
  v.f = f;
  unsigned int i = v.i;
  unsigned int r = (i + 0x7fffu + ((i >> 16) & 1u)) >> 16;  // RNE
  return (unsigned short)r;
}
__device__ __forceinline__ float leaky(float t) {
  return (t >= 0.f) ? t : SLOPE * t;
}
__device__ __forceinline__ bf16x8 cvt8(const float* __restrict__ p) {
  float4 a = *(const float4*)p;
  float4 b = *(const float4*)(p + 4);
  bf16x8 r;
  r[0] = (short)f2b(a.x); r[1] = (short)f2b(a.y);
  r[2] = (short)f2b(a.z); r[3] = (short)f2b(a.w);
  r[4] = (short)f2b(b.x); r[5] = (short)f2b(b.y);
  r[6] = (short)f2b(b.z); r[7] = (short)f2b(b.w);
  return r;
}

// bias + LeakyReLU + LayerNorm(H=128) on MFMA C-layout (col=lane&15,
// row=quad*4+reg; verified R2), params from registers, bf16 store to LDS h.
__device__ __forceinline__ void bias_leaky_ln_store(
    const f32x4* acc, const float* bias, const float* gamma, const float* beta,
    unsigned short* __restrict__ sh, int row0, int lo16, int quad) {
  float v[8][4];
  float s1[4] = {0.f, 0.f, 0.f, 0.f};
  float s2[4] = {0.f, 0.f, 0.f, 0.f};
#pragma unroll
  for (int nt = 0; nt < 8; ++nt) {
#pragma unroll
    for (int r = 0; r < 4; ++r) {
      float t = leaky(acc[nt][r] + bias[nt]);
      v[nt][r] = t;
      s1[r] += t;
      s2[r] += t * t;
    }
  }
#pragma unroll
  for (int r = 0; r < 4; ++r) {
#pragma unroll
    for (int m = 1; m < 16; m <<= 1) {
      s1[r] += __shfl_xor(s1[r], m);
      s2[r] += __shfl_xor(s2[r], m);
    }
  }
  float mu[4], rs[4];
#pragma unroll
  for (int r = 0; r < 4; ++r) {
    mu[r] = s1[r] * (1.0f / 128.0f);
    float var = s2[r] * (1.0f / 128.0f) - mu[r] * mu[r];
    rs[r] = rsqrtf(var + EPS);
  }
#pragma unroll
  for (int nt = 0; nt < 8; ++nt) {
#pragma unroll
    for (int r = 0; r < 4; ++r) {
      float y = (v[nt][r] - mu[r]) * rs[r] * gamma[nt] + beta[nt];
      sh[(row0 + quad * 4 + r) * SH_STRIDE + nt * 16 + lo16] = f2b(y);
    }
  }
}

// prep: blocks 0..15 build per-o bf16 weight images (padded LDS layout);
// blocks 16..1039 convert x to bf16.
__global__ __launch_bounds__(256) void prep(
    const float* __restrict__ x,
    const float* __restrict__ W0, const float* __restrict__ W1,
    const float* __restrict__ W2,
    unsigned short* __restrict__ wimg, unsigned short* __restrict__ xbf) {
  const int bid = blockIdx.x, tid = threadIdx.x;
  if (bid < 16) {
    unsigned short* img = wimg + (size_t)bid * WIMG_SHORTS;
    const float* w0 = W0 + (size_t)bid * HDIM * CIN;
    for (int c = tid; c < (HDIM * CIN) / 8; c += 256) {       // 1024
      int n = c >> 3, k8 = c & 7;
      *(bf16x8*)&img[SW0_OFF + n * SW0_STRIDE + k8 * 8] = cvt8(w0 + c * 8);
    }
    const float* w1 = W1 + (size_t)bid * HDIM * HDIM;
    for (int c = tid; c < (HDIM * HDIM) / 8; c += 256) {      // 2048
      int n = c >> 4, k8 = c & 15;
      *(bf16x8*)&img[SW1_OFF + n * SW1_STRIDE + k8 * 8] = cvt8(w1 + c * 8);
    }
    const float* w2 = W2 + (size_t)bid * F2 * HDIM;
    for (int c = tid; c < (F2 * HDIM) / 8; c += 256) {        // 256
      int n = c >> 4, k8 = c & 15;
      *(bf16x8*)&img[SW2_OFF + n * SW2_STRIDE + k8 * 8] = cvt8(w2 + c * 8);
    }
  } else {
    int idx = (bid - 16) * 256 + tid;                         // 8-elem chunk
    *(bf16x8*)&xbf[(size_t)idx * 8] = cvt8(x + (size_t)idx * 8);
  }
}

// film_main: one block = one o-channel x 256 tokens (4 waves x 4 m-tiles).
// Grid 2048: same-o blocks are bid%16==o -> all land on XCD o%8 under %8
// round-robin -> weight image stays hot in one XCD's L2.
__global__ __launch_bounds__(256, 2) void film_main(
    const unsigned short* __restrict__ xbf,
    const unsigned short* __restrict__ wimg,
    const float* __restrict__ b0, const float* __restrict__ g0,
    const float* __restrict__ be0,
    const float* __restrict__ b1, const float* __restrict__ g1,
    const float* __restrict__ be1,
    const float* __restrict__ b2,
    unsigned short* __restrict__ stg) {
  __shared__ unsigned short smem[SMEM_TOT];
  const int tid  = threadIdx.x;
  const int o    = blockIdx.x & 15;
  const int tok0 = (blockIdx.x >> 4) * 256;

  // stage prebuilt 57.6 KB bf16 weight image (contiguous, no converts)
  {
    const bf16x8* src = (const bf16x8*)(wimg + (size_t)o * WIMG_SHORTS);
    for (int i = tid; i < WIMG_SHORTS / 8; i += 256)          // 3600 chunks
      *(bf16x8*)&smem[i * 8] = src[i];
  }

  const int lane = tid & 63;
  const int wave = tid >> 6;
  const int lo16 = lane & 15;
  const int quad = lane >> 4;
  const int row0 = wave * 16;   // this wave's h-slice (reused per m-tile)

  // preload LN params into registers (reused across 4 m-tiles)
  float p0b[8], p0g[8], p0be[8], p1b[8], p1g[8], p1be[8];
#pragma unroll
  for (int j = 0; j < 8; ++j) {
    p0b[j]  = b0 [o * HDIM + j * 16 + lo16];
    p0g[j]  = g0 [o * HDIM + j * 16 + lo16];
    p0be[j] = be0[o * HDIM + j * 16 + lo16];
    p1b[j]  = b1 [o * HDIM + j * 16 + lo16];
    p1g[j]  = g1 [o * HDIM + j * 16 + lo16];
    p1be[j] = be1[o * HDIM + j * 16 + lo16];
  }
  const float b2v = b2[o * F2 + lo16];
  __syncthreads();

  for (int mt = 0; mt < 4; ++mt) {
    const int trow = tok0 + wave * 64 + mt * 16;   // m-tile's first token

    // ---- Layer 0: [16 tok x 64] @ W0^T -> [16 tok x 128]
    f32x4 acc[8];
#pragma unroll
    for (int nt = 0; nt < 8; ++nt) acc[nt] = (f32x4){0.f, 0.f, 0.f, 0.f};
    {
      const unsigned short* xr = xbf + (size_t)(trow + lo16) * CIN + quad * 8;
#pragma unroll
      for (int ks = 0; ks < 2; ++ks) {
        bf16x8 a = *(const bf16x8*)(xr + ks * 32);
#pragma unroll
        for (int nt = 0; nt < 8; ++nt) {
          bf16x8 b = *(const bf16x8*)
              &smem[SW0_OFF + (nt * 16 + lo16) * SW0_STRIDE + ks * 32 + quad * 8];
          acc[nt] = __builtin_amdgcn_mfma_f32_16x16x32_bf16(a, b, acc[nt], 0, 0, 0);
        }
      }
    }
    bias_leaky_ln_store(acc, p0b, p0g, p0be, smem + SH_OFF, row0, lo16, quad);

    // ---- Layer 1: [16 tok x 128] @ W1^T -> [16 tok x 128]
    // h rows are wave-local; DS ops in-order within a wave -> no barrier.
#pragma unroll
    for (int nt = 0; nt < 8; ++nt) acc[nt] = (f32x4){0.f, 0.f, 0.f, 0.f};
#pragma unroll
    for (int ks = 0; ks < 4; ++ks) {
      bf16x8 a = *(const bf16x8*)
          &smem[SH_OFF + (row0 + lo16) * SH_STRIDE + ks * 32 + quad * 8];
#pragma unroll
      for (int nt = 0; nt < 8; ++nt) {
        bf16x8 b = *(const bf16x8*)
            &smem[SW1_OFF + (nt * 16 + lo16) * SW1_STRIDE + ks * 32 + quad * 8];
        acc[nt] = __builtin_amdgcn_mfma_f32_16x16x32_bf16(a, b, acc[nt], 0, 0, 0);
      }
    }
    bias_leaky_ln_store(acc, p1b, p1g, p1be, smem + SH_OFF, row0, lo16, quad);

    // ---- Layer 2: [16 tok x 128] @ W2^T -> [16 tok x 16]
    f32x4 acc2 = (f32x4){0.f, 0.f, 0.f, 0.f};
#pragma unroll
    for (int ks = 0; ks < 4; ++ks) {
      bf16x8 a = *(const bf16x8*)
          &smem[SH_OFF + (row0 + lo16) * SH_STRIDE + ks * 32 + quad * 8];
      bf16x8 b = *(const bf16x8*)
          &smem[SW2_OFF + lo16 * SW2_STRIDE + ks * 32 + quad * 8];
      acc2 = __builtin_amdgcn_mfma_f32_16x16x32_bf16(a, b, acc2, 0, 0, 0);
    }
#pragma unroll
    for (int r = 0; r < 4; ++r) {
      float y = leaky(acc2[r] + b2v);
      int token = trow + quad * 4 + r;             // f = lo16
      stg[(size_t)o * NTOK * F2 + (size_t)token * F2 + lo16] = f2b(y);
    }
  }
}

// stage bf16 [o][tok][f] -> out fp32 [tok][f][o]. LDS-free: reads are 16B
// vectors over 256B-contiguous runs; each store instr covers 16B-granular
// pieces that L2 write-combines into full lines within the block.
__global__ __launch_bounds__(256) void transpose_out(
    const unsigned short* __restrict__ stg, float* __restrict__ out) {
  const int tid = threadIdx.x;
  const int t0  = blockIdx.x * 8;
  const int o   = tid >> 4;
  const int r   = tid & 15;
  const int t   = t0 + (r >> 1);
  const int half = r & 1;
  bf16x8 v = *(const bf16x8*)&stg[(size_t)o * NTOK * F2 + (size_t)t * F2 + half * 8];
  float* ob = out + (size_t)t * (F2 * O_CH) + half * 8 * O_CH + o;
#pragma unroll
  for (int j = 0; j < 8; ++j) ob[j * O_CH] = b2f((unsigned short)v[j]);
}

extern "C" void kernel_launch(void* const* d_in, const int* in_sizes, int n_in,
                              void* d_out, int out_size, void* d_ws, size_t ws_size,
                              hipStream_t stream) {
  (void)in_sizes; (void)n_in; (void)out_size; (void)ws_size;
  const float* x   = (const float*)d_in[0];
  const float* W0  = (const float*)d_in[1];
  const float* b0  = (const float*)d_in[2];
  const float* g0  = (const float*)d_in[3];
  const float* be0 = (const float*)d_in[4];
  const float* W1  = (const float*)d_in[5];
  const float* b1  = (const float*)d_in[6];
  const float* g1  = (const float*)d_in[7];
  const float* be1 = (const float*)d_in[8];
  const float* W2  = (const float*)d_in[9];
  const float* b2  = (const float*)d_in[10];

  unsigned short* stg  = (unsigned short*)((char*)d_ws + STG_OFF);
  unsigned short* wimg = (unsigned short*)((char*)d_ws + WIMG_OFF);
  unsigned short* xbf  = (unsigned short*)((char*)d_ws + XBF_OFF);

  prep<<<dim3(16 + (NTOK * CIN / 8) / 256), dim3(256), 0, stream>>>(
      x, W0, W1, W2, wimg, xbf);
  film_main<<<dim3(O_CH * (NTOK / 256)), dim3(256), 0, stream>>>(
      xbf, wimg, b0, g0, be0, b1, g1, be1, b2, stg);
  transpose_out<<<dim3(NTOK / 8), dim3(256), 0, stream>>>(stg, (float*)d_out);
}

// Round 4
// 181.234 us; speedup vs baseline: 1.2669x; 1.0973x over previous
//
#include <hip/hip_runtime.h>

// FiLM block, MI355X. I/O fp32; compute bf16 MFMA, fp32 accum.
// R4: swapped MFMA orientation (A=weights, B=tokens) -> C col=token:
//  - LN reduce = 4 shfls (xor16,32) instead of 32
//  - h writes = 8 x ds_write_b64 instead of 32 x ds_write_b16
//  - gamma/beta folded into W1/W2 + bias folds into MFMA acc init (prep)
//  - output store 512B/wave contiguous
#define NTOK  32768
#define CIN   64
#define HDIM  128
#define O_CH  16
#define F2    16
#define SLOPE 0.01f
#define EPS   1e-5f

// LDS weight image (shorts). Rows 16B-aligned, 4-bank rotation/row.
#define SW0_STRIDE 72
#define SW1_STRIDE 136
#define SW2_STRIDE 136
#define SH_STRIDE  136
#define SW0_OFF 0                       // 128 x 72  = 9216
#define SW1_OFF 9216                    // 128 x 136 = 17408
#define SW2_OFF (9216 + 17408)          // 16  x 136 = 2176
#define WIMG_SHORTS 28800               // 57600 B per o-channel
#define SH_OFF  28800                   // 64 rows x 136
#define SMEM_TOT (28800 + 64 * SH_STRIDE)   // 75008 B -> 2 blocks/CU

// d_ws layout (bytes); total ~21.97 MB (ws proven >= 33.5 MB).
#define STG_OFF    0
#define STG_BYTES  ((size_t)O_CH * NTOK * F2 * 2)            // 16 MB
#define WIMG_OFF   STG_BYTES
#define WIMG_BYTES ((size_t)O_CH * WIMG_SHORTS * 2)
#define XBF_OFF    (WIMG_OFF + WIMG_BYTES)
#define XBF_BYTES  ((size_t)NTOK * CIN * 2)
#define B0F_OFF    (XBF_OFF + XBF_BYTES)
#define B0F_BYTES  ((size_t)O_CH * HDIM * 4)
#define B1F_OFF    (B0F_OFF + B0F_BYTES)
#define B1F_BYTES  ((size_t)O_CH * HDIM * 4)
#define B2F_OFF    (B1F_OFF + B1F_BYTES)
#define B2F_BYTES  ((size_t)O_CH * F2 * 4)

typedef __attribute__((ext_vector_type(8))) short bf16x8;
typedef __attribute__((ext_vector_type(4))) short bf16x4;
typedef __attribute__((ext_vector_type(4))) float f32x4;

__device__ __forceinline__ float b2f(unsigned short u) {
  union { unsigned int i; float f; } v;
  v.i = ((unsigned int)u) << 16;
  return v.f;
}
__device__ __forceinline__ unsigned short f2b(float f) {
  union { float f; unsigned int i; } v;
  v.f = f;
  unsigned int i = v.i;
  unsigned int r = (i + 0x7fffu + ((i >> 16) & 1u)) >> 16;  // RNE
  return (unsigned short)r;
}
__device__ __forceinline__ float leaky(float t) {
  return (t >= 0.f) ? t : SLOPE * t;
}
__device__ __forceinline__ bf16x8 cvt8(const float* __restrict__ p) {
  float4 a = *(const float4*)p;
  float4 b = *(const float4*)(p + 4);
  bf16x8 r;
  r[0] = (short)f2b(a.x); r[1] = (short)f2b(a.y);
  r[2] = (short)f2b(a.z); r[3] = (short)f2b(a.w);
  r[4] = (short)f2b(b.x); r[5] = (short)f2b(b.y);
  r[6] = (short)f2b(b.z); r[7] = (short)f2b(b.w);
  return r;
}
// cvt8 with per-element fp32 scale (gamma fold)
__device__ __forceinline__ bf16x8 cvt8s(const float* __restrict__ p,
                                        const float* __restrict__ s) {
  bf16x8 r;
#pragma unroll
  for (int i = 0; i < 8; ++i) r[i] = (short)f2b(p[i] * s[i]);
  return r;
}

// leaky + LayerNorm on swapped C-layout (col=token=lane&15, row=h-dim).
// Lane holds 32 h-values of ONE token: in-lane sums + 2-stage butterfly
// (xor 16, 32) across the 4 quads holding that token. Normalized (t-mu)*rs
// stored bf16 to LDS h[token][h] -- 4 consecutive h per reg -> ds_write_b64.
__device__ __forceinline__ void leaky_ln_store(
    const f32x4* acc, unsigned short* __restrict__ sh,
    int row0, int lo16, int quad) {
  float v[8][4];
  float s1 = 0.f, s2 = 0.f;
#pragma unroll
  for (int nt = 0; nt < 8; ++nt) {
#pragma unroll
    for (int r = 0; r < 4; ++r) {
      float t = leaky(acc[nt][r]);        // bias already in acc (C-init)
      v[nt][r] = t;
      s1 += t;
      s2 += t * t;
    }
  }
  s1 += __shfl_xor(s1, 16); s2 += __shfl_xor(s2, 16);
  s1 += __shfl_xor(s1, 32); s2 += __shfl_xor(s2, 32);
  float mu = s1 * (1.0f / 128.0f);
  float var = s2 * (1.0f / 128.0f) - mu * mu;
  float rs = rsqrtf(var + EPS);
#pragma unroll
  for (int nt = 0; nt < 8; ++nt) {
    bf16x4 p;
#pragma unroll
    for (int r = 0; r < 4; ++r)
      p[r] = (short)f2b((v[nt][r] - mu) * rs);
    *(bf16x4*)&sh[(row0 + lo16) * SH_STRIDE + nt * 16 + quad * 4] = p;
  }
}

// prep: blocks 0..15 build per-o bf16 weight images with gamma folded and
// folded bias vectors; blocks 16+ convert x to bf16.
__global__ __launch_bounds__(256) void prep(
    const float* __restrict__ x,
    const float* __restrict__ W0, const float* __restrict__ b0,
    const float* __restrict__ g0, const float* __restrict__ be0,
    const float* __restrict__ W1, const float* __restrict__ b1,
    const float* __restrict__ g1, const float* __restrict__ be1,
    const float* __restrict__ W2, const float* __restrict__ b2,
    unsigned short* __restrict__ wimg, unsigned short* __restrict__ xbf,
    float* __restrict__ b0f, float* __restrict__ b1f,
    float* __restrict__ b2f) {
  const int bid = blockIdx.x, tid = threadIdx.x;
  if (bid < 16) {
    const int o = bid;
    __shared__ float sg0[HDIM], sbe0[HDIM], sg1[HDIM], sbe1[HDIM];
    if (tid < 128) {
      sg0[tid]  = g0 [o * HDIM + tid];
      sbe0[tid] = be0[o * HDIM + tid];
      sg1[tid]  = g1 [o * HDIM + tid];
      sbe1[tid] = be1[o * HDIM + tid];
    }
    __syncthreads();
    unsigned short* img = wimg + (size_t)o * WIMG_SHORTS;
    const float* w0 = W0 + (size_t)o * HDIM * CIN;
    for (int c = tid; c < (HDIM * CIN) / 8; c += 256) {
      int n = c >> 3, k8 = c & 7;
      *(bf16x8*)&img[SW0_OFF + n * SW0_STRIDE + k8 * 8] = cvt8(w0 + c * 8);
    }
    const float* w1 = W1 + (size_t)o * HDIM * HDIM;
    for (int c = tid; c < (HDIM * HDIM) / 8; c += 256) {
      int n = c >> 4, k8 = c & 15;
      *(bf16x8*)&img[SW1_OFF + n * SW1_STRIDE + k8 * 8] =
          cvt8s(w1 + c * 8, sg0 + k8 * 8);           // W1' = W1 * g0[k]
    }
    const float* w2 = W2 + (size_t)o * F2 * HDIM;
    for (int c = tid; c < (F2 * HDIM) / 8; c += 256) {
      int n = c >> 4, k8 = c & 15;
      *(bf16x8*)&img[SW2_OFF + n * SW2_STRIDE + k8 * 8] =
          cvt8s(w2 + c * 8, sg1 + k8 * 8);           // W2' = W2 * g1[k]
    }
    // folded biases (fp32 exact)
    if (tid < 128) {
      b0f[o * HDIM + tid] = b0[o * HDIM + tid];
      float d = 0.f;
      const float* w1r = w1 + (size_t)tid * HDIM;
      for (int k = 0; k < HDIM; ++k) d += w1r[k] * sbe0[k];
      b1f[o * HDIM + tid] = b1[o * HDIM + tid] + d;  // b1' = b1 + W1*be0
    } else if (tid < 144) {
      int f = tid - 128;
      float d = 0.f;
      const float* w2r = w2 + (size_t)f * HDIM;
      for (int k = 0; k < HDIM; ++k) d += w2r[k] * sbe1[k];
      b2f[o * F2 + f] = b2[o * F2 + f] + d;          // b2' = b2 + W2*be1
    }
  } else {
    int idx = (bid - 16) * 256 + tid;
    *(bf16x8*)&xbf[(size_t)idx * 8] = cvt8(x + (size_t)idx * 8);
  }
}

// film_main: block = one o-channel x 256 tokens (4 waves x 4 m-tiles of 16).
__global__ __launch_bounds__(256, 2) void film_main(
    const unsigned short* __restrict__ xbf,
    const unsigned short* __restrict__ wimg,
    const float* __restrict__ b0f, const float* __restrict__ b1f,
    const float* __restrict__ b2f,
    unsigned short* __restrict__ stg) {
  __shared__ unsigned short smem[SMEM_TOT];
  const int tid  = threadIdx.x;
  const int o    = blockIdx.x & 15;
  const int tok0 = (blockIdx.x >> 4) * 256;

  {  // stage prebuilt 57.6 KB bf16 weight image (contiguous copy)
    const bf16x8* src = (const bf16x8*)(wimg + (size_t)o * WIMG_SHORTS);
    for (int i = tid; i < WIMG_SHORTS / 8; i += 256)
      *(bf16x8*)&smem[i * 8] = src[i];
  }

  const int lane = tid & 63;
  const int wave = tid >> 6;
  const int lo16 = lane & 15;
  const int quad = lane >> 4;
  const int row0 = wave * 16;

  // preload per-lane bias fragments (C-init): h = nt*16 + quad*4 + r
  f32x4 bias0[8], bias1[8];
#pragma unroll
  for (int nt = 0; nt < 8; ++nt) {
    bias0[nt] = *(const f32x4*)&b0f[o * HDIM + nt * 16 + quad * 4];
    bias1[nt] = *(const f32x4*)&b1f[o * HDIM + nt * 16 + quad * 4];
  }
  const f32x4 bias2 = *(const f32x4*)&b2f[o * F2 + quad * 4];
  __syncthreads();

  for (int mt = 0; mt < 4; ++mt) {
    const int trow = tok0 + wave * 64 + mt * 16;

    // ---- Layer 0: A=W0[m=hdim][k], B=x[n=token][k] -> C[col=token][row=h]
    f32x4 acc[8];
#pragma unroll
    for (int nt = 0; nt < 8; ++nt) acc[nt] = bias0[nt];
    {
      const unsigned short* xr = xbf + (size_t)(trow + lo16) * CIN + quad * 8;
#pragma unroll
      for (int ks = 0; ks < 2; ++ks) {
        bf16x8 bx = *(const bf16x8*)(xr + ks * 32);
#pragma unroll
        for (int nt = 0; nt < 8; ++nt) {
          bf16x8 a = *(const bf16x8*)
              &smem[SW0_OFF + (nt * 16 + lo16) * SW0_STRIDE + ks * 32 + quad * 8];
          acc[nt] = __builtin_amdgcn_mfma_f32_16x16x32_bf16(a, bx, acc[nt], 0, 0, 0);
        }
      }
    }
    leaky_ln_store(acc, smem + SH_OFF, row0, lo16, quad);

    // ---- Layer 1: A=W1'[m=hdim][k], B=h[n=token][k]
#pragma unroll
    for (int nt = 0; nt < 8; ++nt) acc[nt] = bias1[nt];
#pragma unroll
    for (int ks = 0; ks < 4; ++ks) {
      bf16x8 bh = *(const bf16x8*)
          &smem[SH_OFF + (row0 + lo16) * SH_STRIDE + ks * 32 + quad * 8];
#pragma unroll
      for (int nt = 0; nt < 8; ++nt) {
        bf16x8 a = *(const bf16x8*)
            &smem[SW1_OFF + (nt * 16 + lo16) * SW1_STRIDE + ks * 32 + quad * 8];
        acc[nt] = __builtin_amdgcn_mfma_f32_16x16x32_bf16(a, bh, acc[nt], 0, 0, 0);
      }
    }
    leaky_ln_store(acc, smem + SH_OFF, row0, lo16, quad);

    // ---- Layer 2: A=W2'[m=f][k], B=h -> C[col=token][row=f]
    f32x4 acc2 = bias2;
#pragma unroll
    for (int ks = 0; ks < 4; ++ks) {
      bf16x8 bh = *(const bf16x8*)
          &smem[SH_OFF + (row0 + lo16) * SH_STRIDE + ks * 32 + quad * 8];
      bf16x8 a = *(const bf16x8*)
          &smem[SW2_OFF + lo16 * SW2_STRIDE + ks * 32 + quad * 8];
      acc2 = __builtin_amdgcn_mfma_f32_16x16x32_bf16(a, bh, acc2, 0, 0, 0);
    }
    {  // lane: token=lo16, f = quad*4 + r (4 consecutive) -> b64 store,
       // wave covers 512B contiguous in stg[o][tok][f]
      bf16x4 p;
#pragma unroll
      for (int r = 0; r < 4; ++r) p[r] = (short)f2b(leaky(acc2[r]));
      *(bf16x4*)&stg[(size_t)o * NTOK * F2 + (size_t)(trow + lo16) * F2 + quad * 4] = p;
    }
  }
}

// transpose: stg bf16 [o][tok][f] -> out fp32 [tok][f][o].
// 64 tokens/block; LDS [o][tok][f] with per-o stride 1032 shorts (bank rot 4).
// Phase1: b128 coalesced reads -> LDS. Phase2: 4 x b16 LDS reads + cvt ->
// float4 stores, 1KB/wave contiguous.
__global__ __launch_bounds__(256) void transpose_out(
    const unsigned short* __restrict__ stg, float* __restrict__ out) {
  __shared__ unsigned short tl[16 * 1032];
  const int tid = threadIdx.x;
  const int t0  = blockIdx.x * 64;
#pragma unroll
  for (int c = tid; c < 2048; c += 256) {
    int o = c >> 7, rem = c & 127;
    *(bf16x8*)&tl[o * 1032 + rem * 8] =
        *(const bf16x8*)&stg[(size_t)o * NTOK * F2 + (size_t)t0 * F2 + rem * 8];
  }
  __syncthreads();
#pragma unroll
  for (int q = tid; q < 4096; q += 256) {
    int t = q >> 6, rest = q & 63, f = rest >> 2, o4 = rest & 3;
    float4 val;
    val.x = b2f(tl[(o4 * 4 + 0) * 1032 + t * 16 + f]);
    val.y = b2f(tl[(o4 * 4 + 1) * 1032 + t * 16 + f]);
    val.z = b2f(tl[(o4 * 4 + 2) * 1032 + t * 16 + f]);
    val.w = b2f(tl[(o4 * 4 + 3) * 1032 + t * 16 + f]);
    *(float4*)&out[(size_t)(t0 + t) * 256 + f * 16 + o4 * 4] = val;
  }
}

extern "C" void kernel_launch(void* const* d_in, const int* in_sizes, int n_in,
                              void* d_out, int out_size, void* d_ws, size_t ws_size,
                              hipStream_t stream) {
  (void)in_sizes; (void)n_in; (void)out_size; (void)ws_size;
  const float* x   = (const float*)d_in[0];
  const float* W0  = (const float*)d_in[1];
  const float* b0  = (const float*)d_in[2];
  const float* g0  = (const float*)d_in[3];
  const float* be0 = (const float*)d_in[4];
  const float* W1  = (const float*)d_in[5];
  const float* b1  = (const float*)d_in[6];
  const float* g1  = (const float*)d_in[7];
  const float* be1 = (const float*)d_in[8];
  const float* W2  = (const float*)d_in[9];
  const float* b2  = (const float*)d_in[10];

  unsigned short* stg  = (unsigned short*)((char*)d_ws + STG_OFF);
  unsigned short* wimg = (unsigned short*)((char*)d_ws + WIMG_OFF);
  unsigned short* xbf  = (unsigned short*)((char*)d_ws + XBF_OFF);
  float* b0f = (float*)((char*)d_ws + B0F_OFF);
  float* b1f = (float*)((char*)d_ws + B1F_OFF);
  float* b2f = (float*)((char*)d_ws + B2F_OFF);

  prep<<<dim3(16 + (NTOK * CIN / 8) / 256), dim3(256), 0, stream>>>(
      x, W0, b0, g0, be0, W1, b1, g1, be1, W2, b2, wimg, xbf, b0f, b1f, b2f);
  film_main<<<dim3(O_CH * (NTOK / 256)), dim3(256), 0, stream>>>(
      xbf, wimg, b0f, b1f, b2f, stg);
  transpose_out<<<dim3(NTOK / 64), dim3(256), 0, stream>>>(stg, (float*)d_out);
}

// Round 6
// 170.186 us; speedup vs baseline: 1.3491x; 1.0649x over previous
//
#include <hip/hip_runtime.h>

// FiLM block, MI355X. I/O fp32; compute bf16 MFMA (A=weights, B=tokens,
// C col=token), fp32 accum. R6 = R4's validated film inner loops, EXACTLY,
// plus: direct fp32 [tok][f][o] output (transpose kernel deleted) and an
// XCD swizzle so the 16 o-blocks of a token range share one XCD's L2
// (full-line write combining of the 4B/sector partial stores).
#define NTOK  32768
#define CIN   64
#define HDIM  128
#define O_CH  16
#define F2    16
#define SLOPE 0.01f
#define EPS   1e-5f

// LDS weight image (shorts). Rows 16B-aligned, 4-bank rotation/row.
#define SW0_STRIDE 72
#define SW1_STRIDE 136
#define SW2_STRIDE 136
#define SH_STRIDE  136
#define SW0_OFF 0                       // 128 x 72  = 9216
#define SW1_OFF 9216                    // 128 x 136 = 17408
#define SW2_OFF (9216 + 17408)          // 16  x 136 = 2176
#define WIMG_SHORTS 28800               // 57600 B per o-channel
#define SH_OFF  28800                   // 64 rows x 136
#define SMEM_TOT (28800 + 64 * SH_STRIDE)   // 75008 B -> 2 blocks/CU

// d_ws layout (bytes); ~5.13 MB total (ws proven >= 33.5 MB).
#define WIMG_OFF   0
#define WIMG_BYTES ((size_t)O_CH * WIMG_SHORTS * 2)          // 921600
#define XBF_OFF    WIMG_BYTES                                 // 16-aligned
#define XBF_BYTES  ((size_t)NTOK * CIN * 2)                  // 4194304
#define B0F_OFF    (XBF_OFF + XBF_BYTES)
#define B0F_BYTES  ((size_t)O_CH * HDIM * 4)
#define B1F_OFF    (B0F_OFF + B0F_BYTES)
#define B1F_BYTES  ((size_t)O_CH * HDIM * 4)
#define B2F_OFF    (B1F_OFF + B1F_BYTES)
#define B2F_BYTES  ((size_t)O_CH * F2 * 4)

typedef __attribute__((ext_vector_type(8))) short bf16x8;
typedef __attribute__((ext_vector_type(4))) short bf16x4;
typedef __attribute__((ext_vector_type(4))) float f32x4;

__device__ __forceinline__ float b2f(unsigned short u) {
  union { unsigned int i; float f; } v;
  v.i = ((unsigned int)u) << 16;
  return v.f;
}
__device__ __forceinline__ unsigned short f2b(float f) {
  union { float f; unsigned int i; } v;
  v.f = f;
  unsigned int i = v.i;
  unsigned int r = (i + 0x7fffu + ((i >> 16) & 1u)) >> 16;  // RNE
  return (unsigned short)r;
}
__device__ __forceinline__ float leaky(float t) {
  return (t >= 0.f) ? t : SLOPE * t;
}
__device__ __forceinline__ bf16x8 cvt8(const float* __restrict__ p) {
  float4 a = *(const float4*)p;
  float4 b = *(const float4*)(p + 4);
  bf16x8 r;
  r[0] = (short)f2b(a.x); r[1] = (short)f2b(a.y);
  r[2] = (short)f2b(a.z); r[3] = (short)f2b(a.w);
  r[4] = (short)f2b(b.x); r[5] = (short)f2b(b.y);
  r[6] = (short)f2b(b.z); r[7] = (short)f2b(b.w);
  return r;
}
__device__ __forceinline__ bf16x8 cvt8s(const float* __restrict__ p,
                                        const float* __restrict__ s) {
  bf16x8 r;
#pragma unroll
  for (int i = 0; i < 8; ++i) r[i] = (short)f2b(p[i] * s[i]);
  return r;
}

// leaky + LayerNorm on C-layout (col=token=lane&15, row=h). Lane holds 32 h
// of one token; butterfly xor 16,32 finishes the 128-sum. Stores (t-mu)*rs
// bf16 to LDS h[token][h] via ds_write_b64. [validated R4]
__device__ __forceinline__ void leaky_ln_store(
    const f32x4* acc, unsigned short* __restrict__ sh,
    int row0, int lo16, int quad) {
  float v[8][4];
  float s1 = 0.f, s2 = 0.f;
#pragma unroll
  for (int nt = 0; nt < 8; ++nt) {
#pragma unroll
    for (int r = 0; r < 4; ++r) {
      float t = leaky(acc[nt][r]);        // bias folded into C-init
      v[nt][r] = t;
      s1 += t;
      s2 += t * t;
    }
  }
  s1 += __shfl_xor(s1, 16); s2 += __shfl_xor(s2, 16);
  s1 += __shfl_xor(s1, 32); s2 += __shfl_xor(s2, 32);
  float mu = s1 * (1.0f / 128.0f);
  float var = s2 * (1.0f / 128.0f) - mu * mu;
  float rs = rsqrtf(var + EPS);
#pragma unroll
  for (int nt = 0; nt < 8; ++nt) {
    bf16x4 p;
#pragma unroll
    for (int r = 0; r < 4; ++r)
      p[r] = (short)f2b((v[nt][r] - mu) * rs);
    *(bf16x4*)&sh[(row0 + lo16) * SH_STRIDE + nt * 16 + quad * 4] = p;
  }
}

// prep: blocks 0..15 build per-o bf16 weight images with gamma folded and
// folded bias vectors; blocks 16+ convert x to bf16. [identical to R4]
__global__ __launch_bounds__(256) void prep(
    const float* __restrict__ x,
    const float* __restrict__ W0, const float* __restrict__ b0,
    const float* __restrict__ g0, const float* __restrict__ be0,
    const float* __restrict__ W1, const float* __restrict__ b1,
    const float* __restrict__ g1, const float* __restrict__ be1,
    const float* __restrict__ W2, const float* __restrict__ b2,
    unsigned short* __restrict__ wimg, unsigned short* __restrict__ xbf,
    float* __restrict__ b0f, float* __restrict__ b1f,
    float* __restrict__ b2f) {
  const int bid = blockIdx.x, tid = threadIdx.x;
  if (bid < 16) {
    const int o = bid;
    __shared__ float sg0[HDIM], sbe0[HDIM], sg1[HDIM], sbe1[HDIM];
    if (tid < 128) {
      sg0[tid]  = g0 [o * HDIM + tid];
      sbe0[tid] = be0[o * HDIM + tid];
      sg1[tid]  = g1 [o * HDIM + tid];
      sbe1[tid] = be1[o * HDIM + tid];
    }
    __syncthreads();
    unsigned short* img = wimg + (size_t)o * WIMG_SHORTS;
    const float* w0 = W0 + (size_t)o * HDIM * CIN;
    for (int c = tid; c < (HDIM * CIN) / 8; c += 256) {
      int n = c >> 3, k8 = c & 7;
      *(bf16x8*)&img[SW0_OFF + n * SW0_STRIDE + k8 * 8] = cvt8(w0 + c * 8);
    }
    const float* w1 = W1 + (size_t)o * HDIM * HDIM;
    for (int c = tid; c < (HDIM * HDIM) / 8; c += 256) {
      int n = c >> 4, k8 = c & 15;
      *(bf16x8*)&img[SW1_OFF + n * SW1_STRIDE + k8 * 8] =
          cvt8s(w1 + c * 8, sg0 + k8 * 8);           // W1' = W1 * g0[k]
    }
    const float* w2 = W2 + (size_t)o * F2 * HDIM;
    for (int c = tid; c < (F2 * HDIM) / 8; c += 256) {
      int n = c >> 4, k8 = c & 15;
      *(bf16x8*)&img[SW2_OFF + n * SW2_STRIDE + k8 * 8] =
          cvt8s(w2 + c * 8, sg1 + k8 * 8);           // W2' = W2 * g1[k]
    }
    if (tid < 128) {
      b0f[o * HDIM + tid] = b0[o * HDIM + tid];
      float d = 0.f;
      const float* w1r = w1 + (size_t)tid * HDIM;
      for (int k = 0; k < HDIM; ++k) d += w1r[k] * sbe0[k];
      b1f[o * HDIM + tid] = b1[o * HDIM + tid] + d;  // b1' = b1 + W1*be0
    } else if (tid < 144) {
      int f = tid - 128;
      float d = 0.f;
      const float* w2r = w2 + (size_t)f * HDIM;
      for (int k = 0; k < HDIM; ++k) d += w2r[k] * sbe1[k];
      b2f[o * F2 + f] = b2[o * F2 + f] + d;          // b2' = b2 + W2*be1
    }
  } else {
    int idx = (bid - 16) * 256 + tid;
    *(bf16x8*)&xbf[(size_t)idx * 8] = cvt8(x + (size_t)idx * 8);
  }
}

// film_main: block = one o x 256 tokens (4 waves x 4 m-tiles). [R4 body]
// bid = q*128 + o*8 + c: the 16 o-blocks of token-group tg=q*8+c share
// XCD c (bid%8) within a 121-bid window -> co-resident -> their 4B/sector
// output writes assemble full 64B lines in that XCD's L2.
__global__ __launch_bounds__(256, 2) void film_main(
    const unsigned short* __restrict__ xbf,
    const unsigned short* __restrict__ wimg,
    const float* __restrict__ b0f, const float* __restrict__ b1f,
    const float* __restrict__ b2f,
    float* __restrict__ out) {
  __shared__ unsigned short smem[SMEM_TOT];
  const int tid = threadIdx.x;
  const int c   = blockIdx.x & 7;
  const int o   = (blockIdx.x >> 3) & 15;
  const int q   = blockIdx.x >> 7;
  const int tok0 = (q * 8 + c) * 256;

  {  // stage prebuilt 57.6 KB bf16 weight image (contiguous copy)
    const bf16x8* src = (const bf16x8*)(wimg + (size_t)o * WIMG_SHORTS);
    for (int i = tid; i < WIMG_SHORTS / 8; i += 256)
      *(bf16x8*)&smem[i * 8] = src[i];
  }

  const int lane = tid & 63;
  const int wave = tid >> 6;
  const int lo16 = lane & 15;
  const int quad = lane >> 4;
  const int row0 = wave * 16;

  // per-lane bias C-init fragments: h-dim = nt*16 + quad*4 + r
  f32x4 bias0[8], bias1[8];
#pragma unroll
  for (int nt = 0; nt < 8; ++nt) {
    bias0[nt] = *(const f32x4*)&b0f[o * HDIM + nt * 16 + quad * 4];
    bias1[nt] = *(const f32x4*)&b1f[o * HDIM + nt * 16 + quad * 4];
  }
  const f32x4 bias2 = *(const f32x4*)&b2f[o * F2 + quad * 4];
  __syncthreads();

  for (int mt = 0; mt < 4; ++mt) {
    const int trow = tok0 + wave * 64 + mt * 16;

    // ---- Layer 0: A=W0 (LDS), B=x tokens -> C[col=token][row=h]
    f32x4 acc[8];
#pragma unroll
    for (int nt = 0; nt < 8; ++nt) acc[nt] = bias0[nt];
    {
      const unsigned short* xr = xbf + (size_t)(trow + lo16) * CIN + quad * 8;
#pragma unroll
      for (int ks = 0; ks < 2; ++ks) {
        bf16x8 bx = *(const bf16x8*)(xr + ks * 32);
#pragma unroll
        for (int nt = 0; nt < 8; ++nt) {
          bf16x8 a = *(const bf16x8*)
              &smem[SW0_OFF + (nt * 16 + lo16) * SW0_STRIDE + ks * 32 + quad * 8];
          acc[nt] = __builtin_amdgcn_mfma_f32_16x16x32_bf16(a, bx, acc[nt], 0, 0, 0);
        }
      }
    }
    leaky_ln_store(acc, smem + SH_OFF, row0, lo16, quad);

    // ---- Layer 1: A=W1' (LDS), B=h
#pragma unroll
    for (int nt = 0; nt < 8; ++nt) acc[nt] = bias1[nt];
#pragma unroll
    for (int ks = 0; ks < 4; ++ks) {
      bf16x8 bh = *(const bf16x8*)
          &smem[SH_OFF + (row0 + lo16) * SH_STRIDE + ks * 32 + quad * 8];
#pragma unroll
      for (int nt = 0; nt < 8; ++nt) {
        bf16x8 a = *(const bf16x8*)
            &smem[SW1_OFF + (nt * 16 + lo16) * SW1_STRIDE + ks * 32 + quad * 8];
        acc[nt] = __builtin_amdgcn_mfma_f32_16x16x32_bf16(a, bh, acc[nt], 0, 0, 0);
      }
    }
    leaky_ln_store(acc, smem + SH_OFF, row0, lo16, quad);

    // ---- Layer 2: A=W2' (LDS), B=h -> C[col=token][row=f]
    f32x4 acc2 = bias2;
#pragma unroll
    for (int ks = 0; ks < 4; ++ks) {
      bf16x8 bh = *(const bf16x8*)
          &smem[SH_OFF + (row0 + lo16) * SH_STRIDE + ks * 32 + quad * 8];
      bf16x8 a = *(const bf16x8*)
          &smem[SW2_OFF + lo16 * SW2_STRIDE + ks * 32 + quad * 8];
      acc2 = __builtin_amdgcn_mfma_f32_16x16x32_bf16(a, bh, acc2, 0, 0, 0);
    }
    // direct fp32 out[tok][f][o]: token=trow+lo16, f=quad*4+r, o fixed.
    // (equals R4's validated stg[o][tok][f] + transpose composition)
    {
      const size_t tb = (size_t)(trow + lo16) * (F2 * O_CH);
#pragma unroll
      for (int r = 0; r < 4; ++r)
        out[tb + (quad * 4 + r) * O_CH + o] = leaky(acc2[r]);
    }
  }
}

extern "C" void kernel_launch(void* const* d_in, const int* in_sizes, int n_in,
                              void* d_out, int out_size, void* d_ws, size_t ws_size,
                              hipStream_t stream) {
  (void)in_sizes; (void)n_in; (void)out_size; (void)ws_size;
  const float* x   = (const float*)d_in[0];
  const float* W0  = (const float*)d_in[1];
  const float* b0  = (const float*)d_in[2];
  const float* g0  = (const float*)d_in[3];
  const float* be0 = (const float*)d_in[4];
  const float* W1  = (const float*)d_in[5];
  const float* b1  = (const float*)d_in[6];
  const float* g1  = (const float*)d_in[7];
  const float* be1 = (const float*)d_in[8];
  const float* W2  = (const float*)d_in[9];
  const float* b2  = (const float*)d_in[10];

  unsigned short* wimg = (unsigned short*)((char*)d_ws + WIMG_OFF);
  unsigned short* xbf  = (unsigned short*)((char*)d_ws + XBF_OFF);
  float* b0f = (float*)((char*)d_ws + B0F_OFF);
  float* b1f = (float*)((char*)d_ws + B1F_OFF);
  float* b2f = (float*)((char*)d_ws + B2F_OFF);

  prep<<<dim3(16 + (NTOK * CIN / 8) / 256), dim3(256), 0, stream>>>(
      x, W0, b0, g0, be0, W1, b1, g1, be1, W2, b2, wimg, xbf, b0f, b1f, b2f);
  film_main<<<dim3(O_CH * (NTOK / 256)), dim3(256), 0, stream>>>(
      xbf, wimg, b0f, b1f, b2f, (float*)d_out);
}